// Round 9
// baseline (341.555 us; speedup 1.0000x reference)
//
#include <hip/hip_runtime.h>
#include <stdint.h>

#define EMBED 1024
#define HEADS 16
#define HDIM 64
#define BATCH 4
#define SEQ 2048
#define ROWS (BATCH*SEQ)   // 8192
#define QROWS 128          // q-rows per attn block

typedef __attribute__((ext_vector_type(8))) __bf16 bf16x8;
typedef __attribute__((ext_vector_type(4))) float f32x4;

#define LDS_U32(p) ((__attribute__((address_space(3))) unsigned int*)(p))
#define GLB_U32(p) ((const __attribute__((address_space(1))) unsigned int*)(p))

__device__ inline unsigned short f2bf(float f) {   // RNE
    union { float f; unsigned int u; } v; v.f = f;
    unsigned int u = v.u;
    return (unsigned short)((u + 0x7FFFu + ((u >> 16) & 1u)) >> 16);
}

// ---------------- fp32 -> bf16 conversion (all 7 arrays, ONE launch) --------
// blocks [0, 24576): activations q,k,v -> xqkv (3 x XE, contiguous)
// blocks [24576, 28672): weights Wq,Wk,Wv,Wo -> wqkvo (4 x WE, contiguous)
__global__ __launch_bounds__(256) void cvt_all(const float* __restrict__ q, const float* __restrict__ k,
                                               const float* __restrict__ v,
                                               const float* __restrict__ wq, const float* __restrict__ wk,
                                               const float* __restrict__ wv, const float* __restrict__ wo,
                                               unsigned short* __restrict__ xqkv,
                                               unsigned short* __restrict__ wqkvo) {
    const size_t XE = (size_t)ROWS * EMBED;
    const size_t WE = (size_t)EMBED * EMBED;
    int g = blockIdx.x;
    const float* src;
    unsigned short* dst;
    size_t off;
    if (g < 24576) {                       // 3 * XE/1024 = 24576
        int arr = g >> 13;                 // XE/1024 = 8192 blocks per array
        src = (arr == 0) ? q : (arr == 1) ? k : v;
        off = (size_t)(g & 8191) * 1024 + threadIdx.x * 4;
        dst = xqkv + (size_t)arr * XE;
    } else {
        int gw = g - 24576;
        int arr = gw >> 10;                // WE/1024 = 1024 blocks per array
        src = (arr == 0) ? wq : (arr == 1) ? wk : (arr == 2) ? wv : wo;
        off = (size_t)(gw & 1023) * 1024 + threadIdx.x * 4;
        dst = wqkvo + (size_t)arr * WE;
    }
    float4 val = *(const float4*)(src + off);
    uint2 p;
    p.x = (unsigned)f2bf(val.x) | ((unsigned)f2bf(val.y) << 16);
    p.y = (unsigned)f2bf(val.z) | ((unsigned)f2bf(val.w) << 16);
    *(uint2*)(dst + off) = p;
}

// ---------------- bf16 GEMM, C = scale*(A @ B^T + bias) ----------------
// 256x256 tile, BK=64, 512 threads (8 waves: 2 M-halves x 4 N-quarters),
// DOUBLE-buffered LDS (128 KB -> 1 block/CU = 2 waves/SIMD) + counted vmcnt
// (T4, round-8 verified skeleton): per iter issue next tile's 8
// global_load_lds per thread, `s_waitcnt vmcnt(8)` (drains exactly the
// current tile's 8, oldest-first), raw s_barrier, MFMA, raw s_barrier.
// 256^2 halves staged bytes per MFMA vs 128^2 (bytes/FLOP ~ 1/BM + 1/BN) and
// doubles per-step compute, fully covering load latency with the same sync.
// XOR-swizzled LDS via source-side swizzle (row-period-8, verified round 3).
// QKV: z selects {Q,K,V}; z==0 applies scale0 (softmax scale folded into Q);
// z==2 (V projection) writes its output TRANSPOSED into vtout (fused
// transpose_v, verified rounds 6-8).
// T1: XCD-chunk swizzle of the linearized block id (grids are %8==0).
template <bool OUT_BF16, bool QKV>
__global__ __launch_bounds__(512, 2) void gemm_bt(const unsigned short* __restrict__ A0,
                                                  const unsigned short* __restrict__ B0,
                                                  const float* __restrict__ bias0,
                                                  const float* __restrict__ bias1,
                                                  const float* __restrict__ bias2,
                                                  void* __restrict__ C0,
                                                  unsigned short* __restrict__ vtout,
                                                  float scale0,
                                                  int M, int N, int K) {
    __shared__ unsigned short As[2][256 * 64];   // 2 x 32 KB
    __shared__ unsigned short Bs[2][256 * 64];   // 2 x 32 KB

    const int tid  = threadIdx.x;
    const int lane = tid & 63;
    const int wave = tid >> 6;          // 0..7
    const int l15  = lane & 15;
    const int quad = lane >> 4;
    const int wm   = wave & 1;          // M-half (128 rows)
    const int wn   = wave >> 1;         // N-quarter (64 cols)

    // XCD swizzle (bijective: all launch grids have nwg % 8 == 0)
    const unsigned nx = gridDim.x, ny = gridDim.y;
    const unsigned nwg = nx * ny * gridDim.z;
    const unsigned lin = (blockIdx.z * ny + blockIdx.y) * nx + blockIdx.x;
    const unsigned swz = (lin & 7) * (nwg >> 3) + (lin >> 3);
    const unsigned bx = swz % nx;
    const unsigned rem = swz / nx;
    const unsigned by = rem % ny;
    const unsigned bz = rem / ny;

    const int tileM = by * 256;
    const int tileN = bx * 256;

    const unsigned short* A = A0;
    const unsigned short* B = B0;
    const float* bias = bias0;
    void* C = C0;
    int z = 0;
    float scale = QKV ? scale0 : 1.0f;
    if (QKV) {
        z = bz;
        A = A0 + (size_t)z * M * K;
        B = B0 + (size_t)z * N * K;
        bias = (z == 0) ? bias0 : (z == 1) ? bias1 : bias2;
        C = (void*)((unsigned short*)C0 + (size_t)z * M * N);
        if (z != 0) scale = 1.0f;
    }

    // preload bias (oldest in vmem queue; drained by the first vmcnt wait)
    float bv4[4];
#pragma unroll
    for (int jn = 0; jn < 4; ++jn)
        bv4[jn] = bias[tileN + wn * 64 + jn * 16 + l15];

    f32x4 acc[8][4] = {};

    // prologue: stage tile 0 into buffer 0 (8 loads/thread: 4 A + 4 B)
#pragma unroll
    for (int s = 0; s < 4; ++s) {
        int j = tid + s * 512;
        int r = j >> 3;                     // 0..255
        int c8 = (j & 7) ^ (r & 7);         // source-side swizzle
        __builtin_amdgcn_global_load_lds(GLB_U32(A + (size_t)(tileM + r) * K + c8 * 8),
                                         LDS_U32(As[0] + j * 8), 16, 0, 0);
        __builtin_amdgcn_global_load_lds(GLB_U32(B + (size_t)(tileN + r) * K + c8 * 8),
                                         LDS_U32(Bs[0] + j * 8), 16, 0, 0);
    }

    const int nt = K >> 6;
    for (int t = 0; t < nt; ++t) {
        const int cur = t & 1;
        if (t + 1 < nt) {
            const int nb = cur ^ 1;
            const int k0 = (t + 1) * 64;
#pragma unroll
            for (int s = 0; s < 4; ++s) {
                int j = tid + s * 512;
                int r = j >> 3;
                int c8 = (j & 7) ^ (r & 7);
                __builtin_amdgcn_global_load_lds(GLB_U32(A + (size_t)(tileM + r) * K + k0 + c8 * 8),
                                                 LDS_U32(As[nb] + j * 8), 16, 0, 0);
                __builtin_amdgcn_global_load_lds(GLB_U32(B + (size_t)(tileN + r) * K + k0 + c8 * 8),
                                                 LDS_U32(Bs[nb] + j * 8), 16, 0, 0);
            }
            asm volatile("s_waitcnt vmcnt(8)" ::: "memory");  // tile t landed; t+1 in flight
        } else {
            asm volatile("s_waitcnt vmcnt(0)" ::: "memory");  // last tile: drain
        }
        __builtin_amdgcn_s_barrier();      // all waves see tile t in LDS

#pragma unroll
        for (int kc = 0; kc < 2; ++kc) {
            bf16x8 a[8], b[4];
#pragma unroll
            for (int i = 0; i < 8; ++i) {
                int ra = wm * 128 + i * 16 + l15;
                a[i] = *(const bf16x8*)(As[cur] + ra * 64 + (((kc * 4 + quad) ^ (ra & 7)) * 8));
            }
#pragma unroll
            for (int i = 0; i < 4; ++i) {
                int rb = wn * 64 + i * 16 + l15;
                b[i] = *(const bf16x8*)(Bs[cur] + rb * 64 + (((kc * 4 + quad) ^ (rb & 7)) * 8));
            }
#pragma unroll
            for (int i = 0; i < 8; ++i)
#pragma unroll
                for (int jn = 0; jn < 4; ++jn)
                    acc[i][jn] = __builtin_amdgcn_mfma_f32_16x16x32_bf16(a[i], b[jn], acc[i][jn], 0, 0, 0);
        }
        __builtin_amdgcn_s_barrier();      // all waves done reading buf[cur]
    }

    if (QKV && z == 2) {
        // V projection: write V^T directly (fused transpose_v).
        // 256-row tiles never cross a batch boundary (2048 % 256 == 0).
#pragma unroll
        for (int i = 0; i < 8; ++i) {
            int row0 = tileM + wm * 128 + i * 16 + (quad << 2);  // b*SEQ + seq0
            int bb   = row0 >> 11;                               // SEQ = 2048
            int seq0 = row0 & (SEQ - 1);
#pragma unroll
            for (int jn = 0; jn < 4; ++jn) {
                int col = tileN + wn * 64 + jn * 16 + l15;       // h*HDIM + d
                float bv = bv4[jn];
                uint2 p;
                p.x = (unsigned)f2bf(acc[i][jn][0] + bv) | ((unsigned)f2bf(acc[i][jn][1] + bv) << 16);
                p.y = (unsigned)f2bf(acc[i][jn][2] + bv) | ((unsigned)f2bf(acc[i][jn][3] + bv) << 16);
                *(uint2*)(vtout + ((size_t)(bb * HEADS) * HDIM + col) * SEQ + seq0) = p;
            }
        }
    } else {
#pragma unroll
        for (int i = 0; i < 8; ++i) {
            int row0 = tileM + wm * 128 + i * 16 + (quad << 2);
#pragma unroll
            for (int jn = 0; jn < 4; ++jn) {
                int col = tileN + wn * 64 + jn * 16 + l15;
                float bv = bv4[jn];
#pragma unroll
                for (int r = 0; r < 4; ++r) {
                    float v = (acc[i][jn][r] + bv) * scale;
                    if (OUT_BF16)
                        ((unsigned short*)C)[(size_t)(row0 + r) * N + col] = f2bf(v);
                    else
                        ((float*)C)[(size_t)(row0 + r) * N + col] = v;
                }
            }
        }
    }
}

// ---------------- flash attention (no-max streaming softmax) ----------------
// Block = 128 q-rows x one (b,h); 4 waves; wave owns rows [32w, 32w+32).
// SWAPPED QK^T: sacc = mfma(K_frag, Q_frag) -> S^T with col=q=l15; P is
// RNE-converted to bf16 in-register and fed straight to the PV MFMA.
// K rows permuted at staging by sigma(r) = (r&35)|((r&12)<<1)|((r&16)>>2)
// to align A-slot and V^T B-slot k-indexing (verified round 2).
// Row sums via MFMA vs all-ones B (row = quad*4+r matches oacc exactly);
// sacc seeded from hoisted zero C; s_setprio(1) around MFMA clusters;
// XCD-chunk swizzle keeps the 16 blocks sharing one (b,h)'s K/V on one XCD.
__global__ __launch_bounds__(256, 4) void attn(const unsigned short* __restrict__ Q,
                                               const unsigned short* __restrict__ Kp,
                                               const unsigned short* __restrict__ Vt,
                                               unsigned short* __restrict__ O) {
    __shared__ unsigned short KVs[2][2][64 * 64];   // [buf][K|V]  32 KB

    const int tid  = threadIdx.x;
    const int lane = tid & 63;
    const int wave = tid >> 6;
    const int l15  = lane & 15;
    const int quad = lane >> 4;

    // XCD swizzle: lin over (b,h,qt), 1024 blocks, chunk = 128 per XCD
    const int lin = ((blockIdx.z * HEADS + blockIdx.y) << 4) | blockIdx.x;
    const int swz = ((lin & 7) << 7) | (lin >> 3);
    const int qt = swz & 15;
    const int h  = (swz >> 4) & 15;
    const int b  = swz >> 8;

    const size_t rowbase = (size_t)b * SEQ;
    const int colbase = h * HDIM;
    const size_t vtbase = (size_t)(b * HEADS + h) * HDIM;

    // prefetch K/V tile 0 into buffer 0 (K rows permuted by sigma)
#pragma unroll
    for (int s = 0; s < 2; ++s) {
        int j = tid + s * 256;
        int r = j >> 3;
        int sr = (r & 35) | ((r & 12) << 1) | ((r & 16) >> 2);
        int c8 = (j & 7) ^ (r & 7);
        __builtin_amdgcn_global_load_lds(GLB_U32(Kp + (rowbase + sr) * EMBED + colbase + c8 * 8),
                                         LDS_U32(KVs[0][0] + j * 8), 16, 0, 0);
        __builtin_amdgcn_global_load_lds(GLB_U32(Vt + (vtbase + r) * SEQ + c8 * 8),
                                         LDS_U32(KVs[0][1] + j * 8), 16, 0, 0);
    }

    // Q fragments straight from global. Softmax scale is pre-folded into Q.
    bf16x8 aq[2][2];
#pragma unroll
    for (int mf = 0; mf < 2; ++mf) {
        const unsigned short* qp =
            Q + (rowbase + qt * QROWS + wave * 32 + mf * 16 + l15) * EMBED + colbase;
#pragma unroll
        for (int ks = 0; ks < 2; ++ks)
            aq[mf][ks] = *(const bf16x8*)(qp + ks * 32 + quad * 8);
    }

    // constants: zero C for first QK MFMA, ones B-fragment for row sums
    const f32x4 fz = {0.0f, 0.0f, 0.0f, 0.0f};
    bf16x8 vone;
#pragma unroll
    for (int i = 0; i < 8; ++i) vone[i] = (__bf16)1.0f;

    f32x4 oacc[2][4] = {};
    f32x4 sumacc[2] = {};

    for (int t = 0; t < 32; ++t) {
        __syncthreads();   // tile t landed (compiler drains vmcnt before s_barrier)
        if (t + 1 < 32) {
            int nb = (t + 1) & 1;
#pragma unroll
            for (int s = 0; s < 2; ++s) {
                int j = tid + s * 256;
                int r = j >> 3;
                int sr = (r & 35) | ((r & 12) << 1) | ((r & 16) >> 2);
                int c8 = (j & 7) ^ (r & 7);
                __builtin_amdgcn_global_load_lds(GLB_U32(Kp + (rowbase + (t + 1) * 64 + sr) * EMBED + colbase + c8 * 8),
                                                 LDS_U32(KVs[nb][0] + j * 8), 16, 0, 0);
                __builtin_amdgcn_global_load_lds(GLB_U32(Vt + (vtbase + r) * SEQ + (t + 1) * 64 + c8 * 8),
                                                 LDS_U32(KVs[nb][1] + j * 8), 16, 0, 0);
            }
        }
        const unsigned short* Ks = KVs[t & 1][0];
        const unsigned short* Vs = KVs[t & 1][1];

        // S'^T = K'.Q'^T ; ks=0 seeds from the hoisted zero (no per-iter init)
        f32x4 sacc[2][4];
        __builtin_amdgcn_s_setprio(1);
#pragma unroll
        for (int nf = 0; nf < 4; ++nf) {
            int krow = nf * 16 + l15;
            int ch = quad ^ (krow & 7);
            bf16x8 bk = *(const bf16x8*)(Ks + krow * 64 + ch * 8);
            sacc[0][nf] = __builtin_amdgcn_mfma_f32_16x16x32_bf16(bk, aq[0][0], fz, 0, 0, 0);
            sacc[1][nf] = __builtin_amdgcn_mfma_f32_16x16x32_bf16(bk, aq[1][0], fz, 0, 0, 0);
        }
#pragma unroll
        for (int nf = 0; nf < 4; ++nf) {
            int krow = nf * 16 + l15;
            int ch = (4 + quad) ^ (krow & 7);
            bf16x8 bk = *(const bf16x8*)(Ks + krow * 64 + ch * 8);
            sacc[0][nf] = __builtin_amdgcn_mfma_f32_16x16x32_bf16(bk, aq[0][1], sacc[0][nf], 0, 0, 0);
            sacc[1][nf] = __builtin_amdgcn_mfma_f32_16x16x32_bf16(bk, aq[1][1], sacc[1][nf], 0, 0, 0);
        }
        __builtin_amdgcn_s_setprio(0);

        // p = exp2(s'); RNE-convert to bf16 PV A-fragments fully in-register.
        // (nf, r) -> fragment [ks = nf>>1], element j = 4*(nf&1) + r.
        bf16x8 apv[2][2];
#pragma unroll
        for (int mf = 0; mf < 2; ++mf)
#pragma unroll
            for (int nf = 0; nf < 4; ++nf) {
                int ks2 = nf >> 1;
                int jb = (nf & 1) * 4;
                apv[mf][ks2][jb + 0] = (__bf16)__builtin_amdgcn_exp2f(sacc[mf][nf][0]);
                apv[mf][ks2][jb + 1] = (__bf16)__builtin_amdgcn_exp2f(sacc[mf][nf][1]);
                apv[mf][ks2][jb + 2] = (__bf16)__builtin_amdgcn_exp2f(sacc[mf][nf][2]);
                apv[mf][ks2][jb + 3] = (__bf16)__builtin_amdgcn_exp2f(sacc[mf][nf][3]);
            }

        // row sums via MFMA (B = ones): out[q][*] = sum_k p, row = quad*4+r
        // O += P.V
        __builtin_amdgcn_s_setprio(1);
#pragma unroll
        for (int ks = 0; ks < 2; ++ks) {
            sumacc[0] = __builtin_amdgcn_mfma_f32_16x16x32_bf16(apv[0][ks], vone, sumacc[0], 0, 0, 0);
            sumacc[1] = __builtin_amdgcn_mfma_f32_16x16x32_bf16(apv[1][ks], vone, sumacc[1], 0, 0, 0);
#pragma unroll
            for (int df = 0; df < 4; ++df) {
                int vrow = df * 16 + l15;
                int ch = (ks * 4 + quad) ^ (vrow & 7);
                bf16x8 bv = *(const bf16x8*)(Vs + vrow * 64 + ch * 8);
                oacc[0][df] = __builtin_amdgcn_mfma_f32_16x16x32_bf16(apv[0][ks], bv, oacc[0][df], 0, 0, 0);
                oacc[1][df] = __builtin_amdgcn_mfma_f32_16x16x32_bf16(apv[1][ks], bv, oacc[1][df], 0, 0, 0);
            }
        }
        __builtin_amdgcn_s_setprio(0);
    }

    // epilogue: sumacc[mf][r] already holds the row sum for row quad*4+r
    // (same mapping as oacc) -> no cross-lane moves needed.
    float rinv[2][4];
#pragma unroll
    for (int mf = 0; mf < 2; ++mf)
#pragma unroll
        for (int r = 0; r < 4; ++r)
            rinv[mf][r] = 1.0f / sumacc[mf][r];

#pragma unroll
    for (int mf = 0; mf < 2; ++mf)
#pragma unroll
        for (int df = 0; df < 4; ++df) {
            int col = colbase + df * 16 + l15;
#pragma unroll
            for (int r = 0; r < 4; ++r) {
                int row = qt * QROWS + wave * 32 + mf * 16 + quad * 4 + r;
                O[(rowbase + row) * EMBED + col] = f2bf(oacc[mf][df][r] * rinv[mf][r]);
            }
        }
}

// ---------------- launch ----------------
extern "C" void kernel_launch(void* const* d_in, const int* in_sizes, int n_in,
                              void* d_out, int out_size, void* d_ws, size_t ws_size,
                              hipStream_t stream) {
    const float* q_in = (const float*)d_in[0];
    const float* k_in = (const float*)d_in[1];
    const float* v_in = (const float*)d_in[2];
    const float* Wq = (const float*)d_in[3];
    const float* bq = (const float*)d_in[4];
    const float* Wk = (const float*)d_in[5];
    const float* bk = (const float*)d_in[6];
    const float* Wv = (const float*)d_in[7];
    const float* bv = (const float*)d_in[8];
    const float* Wo = (const float*)d_in[9];
    const float* bo = (const float*)d_in[10];
    float* out = (float*)d_out;

    const size_t XE = (size_t)ROWS * EMBED;
    const size_t WE = (size_t)EMBED * EMBED;

    unsigned short* ws = (unsigned short*)d_ws;
    unsigned short* xq = ws;            // xq,xk,xv contiguous (fused QKV A-operand)
    unsigned short* wqkvo = xq + 3 * XE;  // 4 weight matrices contiguous
    unsigned short* wo = wqkvo + 3 * WE;
    unsigned short* Qp = wo + WE;       // Qp,Kp contiguous (fused QKV C, z=0/1)
    unsigned short* Kp = Qp + XE;
    unsigned short* vt = Kp + XE;       // V^T (written directly by the V projection)
    unsigned short* Ap = vt + XE;

    const float cexp = 0.045084436f;  // (1/32) * log2(e), folded into Q projection

    cvt_all<<<dim3(28672), 256, 0, stream>>>(q_in, k_in, v_in, Wq, Wk, Wv, Wo, xq, wqkvo);

    // fused Q/K/V projections (Q gets the softmax scale); V written transposed
    gemm_bt<true, true><<<dim3(EMBED / 256, ROWS / 256, 3), 512, 0, stream>>>(
        xq, wqkvo, bq, bk, bv, Qp, vt, cexp, ROWS, EMBED, EMBED);

    attn<<<dim3(SEQ / QROWS, HEADS, BATCH), 256, 0, stream>>>(Qp, Kp, vt, Ap);

    gemm_bt<false, false><<<dim3(EMBED / 256, ROWS / 256), 512, 0, stream>>>(
        Ap, wo, bo, nullptr, nullptr, out, nullptr, 1.0f, ROWS, EMBED, EMBED);
}

// Round 10
// 314.175 us; speedup vs baseline: 1.0871x; 1.0871x over previous
//
#include <hip/hip_runtime.h>
#include <stdint.h>

#define EMBED 1024
#define HEADS 16
#define HDIM 64
#define BATCH 4
#define SEQ 2048
#define ROWS (BATCH*SEQ)   // 8192
#define QROWS 256          // q-rows per attn block (8 waves x 32 rows)

typedef __attribute__((ext_vector_type(8))) __bf16 bf16x8;
typedef __attribute__((ext_vector_type(4))) float f32x4;

#define LDS_U32(p) ((__attribute__((address_space(3))) unsigned int*)(p))
#define GLB_U32(p) ((const __attribute__((address_space(1))) unsigned int*)(p))

__device__ inline unsigned short f2bf(float f) {   // RNE
    union { float f; unsigned int u; } v; v.f = f;
    unsigned int u = v.u;
    return (unsigned short)((u + 0x7FFFu + ((u >> 16) & 1u)) >> 16);
}

// ---------------- fp32 -> bf16 conversion (all 7 arrays, ONE launch) --------
// blocks [0, 24576): activations q,k,v -> xqkv (3 x XE, contiguous)
// blocks [24576, 28672): weights Wq,Wk,Wv,Wo -> wqkvo (4 x WE, contiguous)
__global__ __launch_bounds__(256) void cvt_all(const float* __restrict__ q, const float* __restrict__ k,
                                               const float* __restrict__ v,
                                               const float* __restrict__ wq, const float* __restrict__ wk,
                                               const float* __restrict__ wv, const float* __restrict__ wo,
                                               unsigned short* __restrict__ xqkv,
                                               unsigned short* __restrict__ wqkvo) {
    const size_t XE = (size_t)ROWS * EMBED;
    const size_t WE = (size_t)EMBED * EMBED;
    int g = blockIdx.x;
    const float* src;
    unsigned short* dst;
    size_t off;
    if (g < 24576) {                       // 3 * XE/1024 = 24576
        int arr = g >> 13;                 // XE/1024 = 8192 blocks per array
        src = (arr == 0) ? q : (arr == 1) ? k : v;
        off = (size_t)(g & 8191) * 1024 + threadIdx.x * 4;
        dst = xqkv + (size_t)arr * XE;
    } else {
        int gw = g - 24576;
        int arr = gw >> 10;                // WE/1024 = 1024 blocks per array
        src = (arr == 0) ? wq : (arr == 1) ? wk : (arr == 2) ? wv : wo;
        off = (size_t)(gw & 1023) * 1024 + threadIdx.x * 4;
        dst = wqkvo + (size_t)arr * WE;
    }
    float4 val = *(const float4*)(src + off);
    uint2 p;
    p.x = (unsigned)f2bf(val.x) | ((unsigned)f2bf(val.y) << 16);
    p.y = (unsigned)f2bf(val.z) | ((unsigned)f2bf(val.w) << 16);
    *(uint2*)(dst + off) = p;
}

// ---------------- bf16 GEMM, C = scale*(A @ B^T + bias) ----------------
// ROUND-8 VERIFIED KERNEL, unchanged (256^2 regressed in round 9: grid
// quantization 1.5 rounds + loss of cross-block stagger at 1 block/CU).
// 128x128 tile, BK=64, DOUBLE-buffered LDS + counted vmcnt (T4): per iter
// issue next tile's 8 global_load_lds, `s_waitcnt vmcnt(8)`, raw s_barrier,
// MFMA, raw s_barrier. XOR-swizzled LDS via source-side swizzle.
// QKV: z selects {Q,K,V}; z==0 applies scale0; z==2 writes V^T (fused
// transpose). T1: XCD-chunk swizzle (grids %8==0).
template <bool OUT_BF16, bool QKV>
__global__ __launch_bounds__(256) void gemm_bt(const unsigned short* __restrict__ A0,
                                               const unsigned short* __restrict__ B0,
                                               const float* __restrict__ bias0,
                                               const float* __restrict__ bias1,
                                               const float* __restrict__ bias2,
                                               void* __restrict__ C0,
                                               unsigned short* __restrict__ vtout,
                                               float scale0,
                                               int M, int N, int K) {
    __shared__ unsigned short As[2][128 * 64];
    __shared__ unsigned short Bs[2][128 * 64];

    const int tid  = threadIdx.x;
    const int lane = tid & 63;
    const int wave = tid >> 6;
    const int l15  = lane & 15;
    const int quad = lane >> 4;
    const int wm   = wave & 1;
    const int wn   = wave >> 1;

    // XCD swizzle (bijective: all launch grids have nwg % 8 == 0)
    const unsigned nx = gridDim.x, ny = gridDim.y;
    const unsigned nwg = nx * ny * gridDim.z;
    const unsigned lin = (blockIdx.z * ny + blockIdx.y) * nx + blockIdx.x;
    const unsigned swz = (lin & 7) * (nwg >> 3) + (lin >> 3);
    const unsigned bx = swz % nx;
    const unsigned rem = swz / nx;
    const unsigned by = rem % ny;
    const unsigned bz = rem / ny;

    const int tileM = by * 128;
    const int tileN = bx * 128;

    const unsigned short* A = A0;
    const unsigned short* B = B0;
    const float* bias = bias0;
    void* C = C0;
    int z = 0;
    float scale = QKV ? scale0 : 1.0f;
    if (QKV) {
        z = bz;
        A = A0 + (size_t)z * M * K;
        B = B0 + (size_t)z * N * K;
        bias = (z == 0) ? bias0 : (z == 1) ? bias1 : bias2;
        C = (void*)((unsigned short*)C0 + (size_t)z * M * N);
        if (z != 0) scale = 1.0f;
    }

    // preload bias (oldest in vmem queue; drained by the first vmcnt wait)
    float bv4[4];
#pragma unroll
    for (int jn = 0; jn < 4; ++jn)
        bv4[jn] = bias[tileN + wn * 64 + jn * 16 + l15];

    f32x4 acc[4][4] = {};

    // prologue: stage tile 0 into buffer 0
#pragma unroll
    for (int s = 0; s < 4; ++s) {
        int j = tid + s * 256;
        int r = j >> 3;
        int c8 = (j & 7) ^ (r & 7);         // source-side swizzle
        __builtin_amdgcn_global_load_lds(GLB_U32(A + (size_t)(tileM + r) * K + c8 * 8),
                                         LDS_U32(As[0] + j * 8), 16, 0, 0);
        __builtin_amdgcn_global_load_lds(GLB_U32(B + (size_t)(tileN + r) * K + c8 * 8),
                                         LDS_U32(Bs[0] + j * 8), 16, 0, 0);
    }

    const int nt = K >> 6;
    for (int t = 0; t < nt; ++t) {
        const int cur = t & 1;
        if (t + 1 < nt) {
            const int nb = cur ^ 1;
            const int k0 = (t + 1) * 64;
#pragma unroll
            for (int s = 0; s < 4; ++s) {
                int j = tid + s * 256;
                int r = j >> 3;
                int c8 = (j & 7) ^ (r & 7);
                __builtin_amdgcn_global_load_lds(GLB_U32(A + (size_t)(tileM + r) * K + k0 + c8 * 8),
                                                 LDS_U32(As[nb] + j * 8), 16, 0, 0);
                __builtin_amdgcn_global_load_lds(GLB_U32(B + (size_t)(tileN + r) * K + k0 + c8 * 8),
                                                 LDS_U32(Bs[nb] + j * 8), 16, 0, 0);
            }
            asm volatile("s_waitcnt vmcnt(8)" ::: "memory");  // tile t landed; t+1 in flight
        } else {
            asm volatile("s_waitcnt vmcnt(0)" ::: "memory");  // last tile: drain
        }
        __builtin_amdgcn_s_barrier();      // all waves see tile t in LDS

#pragma unroll
        for (int kc = 0; kc < 2; ++kc) {
            bf16x8 a[4], b[4];
#pragma unroll
            for (int i = 0; i < 4; ++i) {
                int ra = wm * 64 + i * 16 + l15;
                a[i] = *(const bf16x8*)(As[cur] + ra * 64 + (((kc * 4 + quad) ^ (ra & 7)) * 8));
                int rb = wn * 64 + i * 16 + l15;
                b[i] = *(const bf16x8*)(Bs[cur] + rb * 64 + (((kc * 4 + quad) ^ (rb & 7)) * 8));
            }
#pragma unroll
            for (int i = 0; i < 4; ++i)
#pragma unroll
                for (int jn = 0; jn < 4; ++jn)
                    acc[i][jn] = __builtin_amdgcn_mfma_f32_16x16x32_bf16(a[i], b[jn], acc[i][jn], 0, 0, 0);
        }
        __builtin_amdgcn_s_barrier();      // all waves done reading buf[cur]
    }

    if (QKV && z == 2) {
        // V projection: write V^T directly (fused transpose_v).
#pragma unroll
        for (int i = 0; i < 4; ++i) {
            int row0 = tileM + wm * 64 + i * 16 + (quad << 2);   // b*SEQ + seq0
            int bb   = row0 >> 11;                               // SEQ = 2048
            int seq0 = row0 & (SEQ - 1);
#pragma unroll
            for (int jn = 0; jn < 4; ++jn) {
                int col = tileN + wn * 64 + jn * 16 + l15;       // h*HDIM + d
                float bv = bv4[jn];
                uint2 p;
                p.x = (unsigned)f2bf(acc[i][jn][0] + bv) | ((unsigned)f2bf(acc[i][jn][1] + bv) << 16);
                p.y = (unsigned)f2bf(acc[i][jn][2] + bv) | ((unsigned)f2bf(acc[i][jn][3] + bv) << 16);
                *(uint2*)(vtout + ((size_t)(bb * HEADS) * HDIM + col) * SEQ + seq0) = p;
            }
        }
    } else {
#pragma unroll
        for (int i = 0; i < 4; ++i) {
            int row0 = tileM + wm * 64 + i * 16 + (quad << 2);
#pragma unroll
            for (int jn = 0; jn < 4; ++jn) {
                int col = tileN + wn * 64 + jn * 16 + l15;
                float bv = bv4[jn];
#pragma unroll
                for (int r = 0; r < 4; ++r) {
                    float v = (acc[i][jn][r] + bv) * scale;
                    if (OUT_BF16)
                        ((unsigned short*)C)[(size_t)(row0 + r) * N + col] = f2bf(v);
                    else
                        ((float*)C)[(size_t)(row0 + r) * N + col] = v;
                }
            }
        }
    }
}

// ---------------- flash attention (no-max streaming softmax) ----------------
// NEW: 512 threads, 8 waves, QROWS=256 — per-wave compute code is byte-
// identical to the verified 4-wave version (wave owns rows [32w,32w+32));
// the same 16 KB K/V tile now serves 2x the q-rows (staged bytes per q-row
// halve, barrier events halve). Sync = the round-8 VERIFIED counted-vmcnt
// skeleton: {stage(t+1) -> s_waitcnt vmcnt(2) -> s_barrier -> compute ->
// s_barrier} (per-wave drain before the shared barrier; 2 loads/thread/tile).
// SWAPPED QK^T (S^T, col=q=l15); P RNE-cast to bf16 in-register; K rows
// permuted at staging by sigma(r) = (r&35)|((r&12)<<1)|((r&16)>>2); row sums
// via MFMA vs all-ones B; sacc seeded from hoisted zero; s_setprio around
// MFMA clusters; XCD-chunk swizzle keeps the 8 blocks sharing one (b,h)'s
// K/V on one XCD (8 bh-pairs x 0.5 MB = 4 MB = one XCD L2).
__global__ __launch_bounds__(512, 4) void attn(const unsigned short* __restrict__ Q,
                                               const unsigned short* __restrict__ Kp,
                                               const unsigned short* __restrict__ Vt,
                                               unsigned short* __restrict__ O) {
    __shared__ unsigned short KVs[2][2][64 * 64];   // [buf][K|V]  32 KB

    const int tid  = threadIdx.x;
    const int lane = tid & 63;
    const int wave = tid >> 6;          // 0..7
    const int l15  = lane & 15;
    const int quad = lane >> 4;

    // XCD swizzle: lin over (b,h,qt), 512 blocks, chunk = 64 per XCD
    const int lin = ((blockIdx.z * HEADS + blockIdx.y) << 3) | blockIdx.x;
    const int swz = ((lin & 7) << 6) | (lin >> 3);
    const int qt = swz & 7;
    const int h  = (swz >> 3) & 15;
    const int b  = swz >> 7;

    const size_t rowbase = (size_t)b * SEQ;
    const int colbase = h * HDIM;
    const size_t vtbase = (size_t)(b * HEADS + h) * HDIM;

    // prologue: stage K/V tile 0 into buffer 0 (K rows permuted by sigma);
    // 512 threads x 1 slot each per operand (64x64 bf16 = 512 x 16B slots)
    {
        int j = tid;
        int r = j >> 3;
        int sr = (r & 35) | ((r & 12) << 1) | ((r & 16) >> 2);
        int c8 = (j & 7) ^ (r & 7);
        __builtin_amdgcn_global_load_lds(GLB_U32(Kp + (rowbase + sr) * EMBED + colbase + c8 * 8),
                                         LDS_U32(KVs[0][0] + j * 8), 16, 0, 0);
        __builtin_amdgcn_global_load_lds(GLB_U32(Vt + (vtbase + r) * SEQ + c8 * 8),
                                         LDS_U32(KVs[0][1] + j * 8), 16, 0, 0);
    }

    // Q fragments straight from global (drained by the first vmcnt wait,
    // as they are older in the queue than tile 1's loads).
    bf16x8 aq[2][2];
#pragma unroll
    for (int mf = 0; mf < 2; ++mf) {
        const unsigned short* qp =
            Q + (rowbase + qt * QROWS + wave * 32 + mf * 16 + l15) * EMBED + colbase;
#pragma unroll
        for (int ks = 0; ks < 2; ++ks)
            aq[mf][ks] = *(const bf16x8*)(qp + ks * 32 + quad * 8);
    }

    // constants: zero C for first QK MFMA, ones B-fragment for row sums
    const f32x4 fz = {0.0f, 0.0f, 0.0f, 0.0f};
    bf16x8 vone;
#pragma unroll
    for (int i = 0; i < 8; ++i) vone[i] = (__bf16)1.0f;

    f32x4 oacc[2][4] = {};
    f32x4 sumacc[2] = {};

    for (int t = 0; t < 32; ++t) {
        const int cur = t & 1;
        if (t + 1 < 32) {
            int nb = cur ^ 1;
            int j = tid;
            int r = j >> 3;
            int sr = (r & 35) | ((r & 12) << 1) | ((r & 16) >> 2);
            int c8 = (j & 7) ^ (r & 7);
            __builtin_amdgcn_global_load_lds(GLB_U32(Kp + (rowbase + (t + 1) * 64 + sr) * EMBED + colbase + c8 * 8),
                                             LDS_U32(KVs[nb][0] + j * 8), 16, 0, 0);
            __builtin_amdgcn_global_load_lds(GLB_U32(Vt + (vtbase + r) * SEQ + (t + 1) * 64 + c8 * 8),
                                             LDS_U32(KVs[nb][1] + j * 8), 16, 0, 0);
            asm volatile("s_waitcnt vmcnt(2)" ::: "memory");  // tile t landed; t+1 in flight
        } else {
            asm volatile("s_waitcnt vmcnt(0)" ::: "memory");  // last tile: drain
        }
        __builtin_amdgcn_s_barrier();      // all waves see tile t in LDS

        const unsigned short* Ks = KVs[cur][0];
        const unsigned short* Vs = KVs[cur][1];

        // S'^T = K'.Q'^T ; ks=0 seeds from the hoisted zero (no per-iter init)
        f32x4 sacc[2][4];
        __builtin_amdgcn_s_setprio(1);
#pragma unroll
        for (int nf = 0; nf < 4; ++nf) {
            int krow = nf * 16 + l15;
            int ch = quad ^ (krow & 7);
            bf16x8 bk = *(const bf16x8*)(Ks + krow * 64 + ch * 8);
            sacc[0][nf] = __builtin_amdgcn_mfma_f32_16x16x32_bf16(bk, aq[0][0], fz, 0, 0, 0);
            sacc[1][nf] = __builtin_amdgcn_mfma_f32_16x16x32_bf16(bk, aq[1][0], fz, 0, 0, 0);
        }
#pragma unroll
        for (int nf = 0; nf < 4; ++nf) {
            int krow = nf * 16 + l15;
            int ch = (4 + quad) ^ (krow & 7);
            bf16x8 bk = *(const bf16x8*)(Ks + krow * 64 + ch * 8);
            sacc[0][nf] = __builtin_amdgcn_mfma_f32_16x16x32_bf16(bk, aq[0][1], sacc[0][nf], 0, 0, 0);
            sacc[1][nf] = __builtin_amdgcn_mfma_f32_16x16x32_bf16(bk, aq[1][1], sacc[1][nf], 0, 0, 0);
        }
        __builtin_amdgcn_s_setprio(0);

        // p = exp2(s'); RNE-convert to bf16 PV A-fragments fully in-register.
        // (nf, r) -> fragment [ks = nf>>1], element j = 4*(nf&1) + r.
        bf16x8 apv[2][2];
#pragma unroll
        for (int mf = 0; mf < 2; ++mf)
#pragma unroll
            for (int nf = 0; nf < 4; ++nf) {
                int ks2 = nf >> 1;
                int jb = (nf & 1) * 4;
                apv[mf][ks2][jb + 0] = (__bf16)__builtin_amdgcn_exp2f(sacc[mf][nf][0]);
                apv[mf][ks2][jb + 1] = (__bf16)__builtin_amdgcn_exp2f(sacc[mf][nf][1]);
                apv[mf][ks2][jb + 2] = (__bf16)__builtin_amdgcn_exp2f(sacc[mf][nf][2]);
                apv[mf][ks2][jb + 3] = (__bf16)__builtin_amdgcn_exp2f(sacc[mf][nf][3]);
            }

        // row sums via MFMA (B = ones): out[q][*] = sum_k p, row = quad*4+r
        // O += P.V
        __builtin_amdgcn_s_setprio(1);
#pragma unroll
        for (int ks = 0; ks < 2; ++ks) {
            sumacc[0] = __builtin_amdgcn_mfma_f32_16x16x32_bf16(apv[0][ks], vone, sumacc[0], 0, 0, 0);
            sumacc[1] = __builtin_amdgcn_mfma_f32_16x16x32_bf16(apv[1][ks], vone, sumacc[1], 0, 0, 0);
#pragma unroll
            for (int df = 0; df < 4; ++df) {
                int vrow = df * 16 + l15;
                int ch = (ks * 4 + quad) ^ (vrow & 7);
                bf16x8 bv = *(const bf16x8*)(Vs + vrow * 64 + ch * 8);
                oacc[0][df] = __builtin_amdgcn_mfma_f32_16x16x32_bf16(apv[0][ks], bv, oacc[0][df], 0, 0, 0);
                oacc[1][df] = __builtin_amdgcn_mfma_f32_16x16x32_bf16(apv[1][ks], bv, oacc[1][df], 0, 0, 0);
            }
        }
        __builtin_amdgcn_s_setprio(0);
        __builtin_amdgcn_s_barrier();      // all waves done reading buf[cur]
    }

    // epilogue: sumacc[mf][r] already holds the row sum for row quad*4+r
    // (same mapping as oacc) -> no cross-lane moves needed.
    float rinv[2][4];
#pragma unroll
    for (int mf = 0; mf < 2; ++mf)
#pragma unroll
        for (int r = 0; r < 4; ++r)
            rinv[mf][r] = 1.0f / sumacc[mf][r];

#pragma unroll
    for (int mf = 0; mf < 2; ++mf)
#pragma unroll
        for (int df = 0; df < 4; ++df) {
            int col = colbase + df * 16 + l15;
#pragma unroll
            for (int r = 0; r < 4; ++r) {
                int row = qt * QROWS + wave * 32 + mf * 16 + quad * 4 + r;
                O[(rowbase + row) * EMBED + col] = f2bf(oacc[mf][df][r] * rinv[mf][r]);
            }
        }
}

// ---------------- launch ----------------
extern "C" void kernel_launch(void* const* d_in, const int* in_sizes, int n_in,
                              void* d_out, int out_size, void* d_ws, size_t ws_size,
                              hipStream_t stream) {
    const float* q_in = (const float*)d_in[0];
    const float* k_in = (const float*)d_in[1];
    const float* v_in = (const float*)d_in[2];
    const float* Wq = (const float*)d_in[3];
    const float* bq = (const float*)d_in[4];
    const float* Wk = (const float*)d_in[5];
    const float* bk = (const float*)d_in[6];
    const float* Wv = (const float*)d_in[7];
    const float* bv = (const float*)d_in[8];
    const float* Wo = (const float*)d_in[9];
    const float* bo = (const float*)d_in[10];
    float* out = (float*)d_out;

    const size_t XE = (size_t)ROWS * EMBED;
    const size_t WE = (size_t)EMBED * EMBED;

    unsigned short* ws = (unsigned short*)d_ws;
    unsigned short* xq = ws;            // xq,xk,xv contiguous (fused QKV A-operand)
    unsigned short* wqkvo = xq + 3 * XE;  // 4 weight matrices contiguous
    unsigned short* wo = wqkvo + 3 * WE;
    unsigned short* Qp = wo + WE;       // Qp,Kp contiguous (fused QKV C, z=0/1)
    unsigned short* Kp = Qp + XE;
    unsigned short* vt = Kp + XE;       // V^T (written directly by the V projection)
    unsigned short* Ap = vt + XE;

    const float cexp = 0.045084436f;  // (1/32) * log2(e), folded into Q projection

    cvt_all<<<dim3(28672), 256, 0, stream>>>(q_in, k_in, v_in, Wq, Wk, Wv, Wo, xq, wqkvo);

    // fused Q/K/V projections (Q gets the softmax scale); V written transposed
    gemm_bt<true, true><<<dim3(EMBED / 128, ROWS / 128, 3), 256, 0, stream>>>(
        xq, wqkvo, bq, bk, bv, Qp, vt, cexp, ROWS, EMBED, EMBED);

    attn<<<dim3(SEQ / QROWS, HEADS, BATCH), 512, 0, stream>>>(Qp, Kp, vt, Ap);

    gemm_bt<false, false><<<dim3(EMBED / 128, ROWS / 128), 256, 0, stream>>>(
        Ap, wo, bo, nullptr, nullptr, out, nullptr, 1.0f, ROWS, EMBED, EMBED);
}

// Round 11
// 302.523 us; speedup vs baseline: 1.1290x; 1.0385x over previous
//
#include <hip/hip_runtime.h>
#include <stdint.h>

#define EMBED 1024
#define HEADS 16
#define HDIM 64
#define BATCH 4
#define SEQ 2048
#define ROWS (BATCH*SEQ)   // 8192
#define QROWS 256          // q-rows per attn block (8 waves x 32 rows)

typedef __attribute__((ext_vector_type(8))) __bf16 bf16x8;
typedef __attribute__((ext_vector_type(4))) float f32x4;

#define LDS_U32(p) ((__attribute__((address_space(3))) unsigned int*)(p))
#define GLB_U32(p) ((const __attribute__((address_space(1))) unsigned int*)(p))

__device__ inline unsigned short f2bf(float f) {   // RNE
    union { float f; unsigned int u; } v; v.f = f;
    unsigned int u = v.u;
    return (unsigned short)((u + 0x7FFFu + ((u >> 16) & 1u)) >> 16);
}

// ---------------- fp32 -> bf16 conversion (all 7 arrays, ONE launch) --------
// blocks [0, 24576): activations q,k,v -> xqkv (3 x XE, contiguous)
// blocks [24576, 28672): weights Wq,Wk,Wv,Wo -> wqkvo (4 x WE, contiguous)
__global__ __launch_bounds__(256) void cvt_all(const float* __restrict__ q, const float* __restrict__ k,
                                               const float* __restrict__ v,
                                               const float* __restrict__ wq, const float* __restrict__ wk,
                                               const float* __restrict__ wv, const float* __restrict__ wo,
                                               unsigned short* __restrict__ xqkv,
                                               unsigned short* __restrict__ wqkvo) {
    const size_t XE = (size_t)ROWS * EMBED;
    const size_t WE = (size_t)EMBED * EMBED;
    int g = blockIdx.x;
    const float* src;
    unsigned short* dst;
    size_t off;
    if (g < 24576) {                       // 3 * XE/1024 = 24576
        int arr = g >> 13;                 // XE/1024 = 8192 blocks per array
        src = (arr == 0) ? q : (arr == 1) ? k : v;
        off = (size_t)(g & 8191) * 1024 + threadIdx.x * 4;
        dst = xqkv + (size_t)arr * XE;
    } else {
        int gw = g - 24576;
        int arr = gw >> 10;                // WE/1024 = 1024 blocks per array
        src = (arr == 0) ? wq : (arr == 1) ? wk : (arr == 2) ? wv : wo;
        off = (size_t)(gw & 1023) * 1024 + threadIdx.x * 4;
        dst = wqkvo + (size_t)arr * WE;
    }
    float4 val = *(const float4*)(src + off);
    uint2 p;
    p.x = (unsigned)f2bf(val.x) | ((unsigned)f2bf(val.y) << 16);
    p.y = (unsigned)f2bf(val.z) | ((unsigned)f2bf(val.w) << 16);
    *(uint2*)(dst + off) = p;
}

// ---------------- bf16 GEMM, C = scale*(A @ B^T + bias) ----------------
// 128x128 tile, BK=64, DOUBLE-buffered LDS + counted vmcnt (T4, round-8
// verified skeleton) — NOW 512 THREADS / 8 WAVES: wave (wm=wave&1,
// wn=wave>>1) owns a 64x32 output (acc[4][2]). LDS layout, swizzle, byte
// addresses, grids are IDENTICAL to the round-8 kernel; only the
// wave->fragment assignment and per-thread staging count change (4
// loads/thread -> vmcnt(4)). 2 blocks/CU x 8 waves = 4 waves/SIMD: two
// independent barrier domains hide the stage+vmcnt+barrier envelope that
// held MfmaUtil at 28% (round-10 profile: all pipes <=28%, ~50% idle).
// QKV: z selects {Q,K,V}; z==0 applies scale0 (softmax scale folded into Q);
// z==2 writes V^T directly (fused transpose, verified rounds 6-10).
// T1: XCD-chunk swizzle of the linearized block id (grids are %8==0).
template <bool OUT_BF16, bool QKV>
__global__ __launch_bounds__(512, 4) void gemm_bt(const unsigned short* __restrict__ A0,
                                                  const unsigned short* __restrict__ B0,
                                                  const float* __restrict__ bias0,
                                                  const float* __restrict__ bias1,
                                                  const float* __restrict__ bias2,
                                                  void* __restrict__ C0,
                                                  unsigned short* __restrict__ vtout,
                                                  float scale0,
                                                  int M, int N, int K) {
    __shared__ unsigned short As[2][128 * 64];
    __shared__ unsigned short Bs[2][128 * 64];

    const int tid  = threadIdx.x;
    const int lane = tid & 63;
    const int wave = tid >> 6;          // 0..7
    const int l15  = lane & 15;
    const int quad = lane >> 4;
    const int wm   = wave & 1;          // M-half (64 rows)
    const int wn   = wave >> 1;         // N-quarter (32 cols)

    // XCD swizzle (bijective: all launch grids have nwg % 8 == 0)
    const unsigned nx = gridDim.x, ny = gridDim.y;
    const unsigned nwg = nx * ny * gridDim.z;
    const unsigned lin = (blockIdx.z * ny + blockIdx.y) * nx + blockIdx.x;
    const unsigned swz = (lin & 7) * (nwg >> 3) + (lin >> 3);
    const unsigned bx = swz % nx;
    const unsigned rem = swz / nx;
    const unsigned by = rem % ny;
    const unsigned bz = rem / ny;

    const int tileM = by * 128;
    const int tileN = bx * 128;

    const unsigned short* A = A0;
    const unsigned short* B = B0;
    const float* bias = bias0;
    void* C = C0;
    int z = 0;
    float scale = QKV ? scale0 : 1.0f;
    if (QKV) {
        z = bz;
        A = A0 + (size_t)z * M * K;
        B = B0 + (size_t)z * N * K;
        bias = (z == 0) ? bias0 : (z == 1) ? bias1 : bias2;
        C = (void*)((unsigned short*)C0 + (size_t)z * M * N);
        if (z != 0) scale = 1.0f;
    }

    // preload bias (oldest in vmem queue; drained by the first vmcnt wait)
    float bv2[2];
#pragma unroll
    for (int jn = 0; jn < 2; ++jn)
        bv2[jn] = bias[tileN + wn * 32 + jn * 16 + l15];

    f32x4 acc[4][2] = {};

    // prologue: stage tile 0 into buffer 0 (4 loads/thread: 2 A + 2 B)
#pragma unroll
    for (int s = 0; s < 2; ++s) {
        int j = tid + s * 512;
        int r = j >> 3;
        int c8 = (j & 7) ^ (r & 7);         // source-side swizzle
        __builtin_amdgcn_global_load_lds(GLB_U32(A + (size_t)(tileM + r) * K + c8 * 8),
                                         LDS_U32(As[0] + j * 8), 16, 0, 0);
        __builtin_amdgcn_global_load_lds(GLB_U32(B + (size_t)(tileN + r) * K + c8 * 8),
                                         LDS_U32(Bs[0] + j * 8), 16, 0, 0);
    }

    const int nt = K >> 6;
    for (int t = 0; t < nt; ++t) {
        const int cur = t & 1;
        if (t + 1 < nt) {
            const int nb = cur ^ 1;
            const int k0 = (t + 1) * 64;
#pragma unroll
            for (int s = 0; s < 2; ++s) {
                int j = tid + s * 512;
                int r = j >> 3;
                int c8 = (j & 7) ^ (r & 7);
                __builtin_amdgcn_global_load_lds(GLB_U32(A + (size_t)(tileM + r) * K + k0 + c8 * 8),
                                                 LDS_U32(As[nb] + j * 8), 16, 0, 0);
                __builtin_amdgcn_global_load_lds(GLB_U32(B + (size_t)(tileN + r) * K + k0 + c8 * 8),
                                                 LDS_U32(Bs[nb] + j * 8), 16, 0, 0);
            }
            asm volatile("s_waitcnt vmcnt(4)" ::: "memory");  // tile t landed; t+1 in flight
        } else {
            asm volatile("s_waitcnt vmcnt(0)" ::: "memory");  // last tile: drain
        }
        __builtin_amdgcn_s_barrier();      // all waves see tile t in LDS

#pragma unroll
        for (int kc = 0; kc < 2; ++kc) {
            bf16x8 a[4], b[2];
#pragma unroll
            for (int i = 0; i < 4; ++i) {
                int ra = wm * 64 + i * 16 + l15;
                a[i] = *(const bf16x8*)(As[cur] + ra * 64 + (((kc * 4 + quad) ^ (ra & 7)) * 8));
            }
#pragma unroll
            for (int jn = 0; jn < 2; ++jn) {
                int rb = wn * 32 + jn * 16 + l15;
                b[jn] = *(const bf16x8*)(Bs[cur] + rb * 64 + (((kc * 4 + quad) ^ (rb & 7)) * 8));
            }
#pragma unroll
            for (int i = 0; i < 4; ++i)
#pragma unroll
                for (int jn = 0; jn < 2; ++jn)
                    acc[i][jn] = __builtin_amdgcn_mfma_f32_16x16x32_bf16(a[i], b[jn], acc[i][jn], 0, 0, 0);
        }
        __builtin_amdgcn_s_barrier();      // all waves done reading buf[cur]
    }

    if (QKV && z == 2) {
        // V projection: write V^T directly (fused transpose_v).
#pragma unroll
        for (int i = 0; i < 4; ++i) {
            int row0 = tileM + wm * 64 + i * 16 + (quad << 2);   // b*SEQ + seq0
            int bb   = row0 >> 11;                               // SEQ = 2048
            int seq0 = row0 & (SEQ - 1);
#pragma unroll
            for (int jn = 0; jn < 2; ++jn) {
                int col = tileN + wn * 32 + jn * 16 + l15;       // h*HDIM + d
                float bv = bv2[jn];
                uint2 p;
                p.x = (unsigned)f2bf(acc[i][jn][0] + bv) | ((unsigned)f2bf(acc[i][jn][1] + bv) << 16);
                p.y = (unsigned)f2bf(acc[i][jn][2] + bv) | ((unsigned)f2bf(acc[i][jn][3] + bv) << 16);
                *(uint2*)(vtout + ((size_t)(bb * HEADS) * HDIM + col) * SEQ + seq0) = p;
            }
        }
    } else {
#pragma unroll
        for (int i = 0; i < 4; ++i) {
            int row0 = tileM + wm * 64 + i * 16 + (quad << 2);
#pragma unroll
            for (int jn = 0; jn < 2; ++jn) {
                int col = tileN + wn * 32 + jn * 16 + l15;
                float bv = bv2[jn];
#pragma unroll
                for (int r = 0; r < 4; ++r) {
                    float v = (acc[i][jn][r] + bv) * scale;
                    if (OUT_BF16)
                        ((unsigned short*)C)[(size_t)(row0 + r) * N + col] = f2bf(v);
                    else
                        ((float*)C)[(size_t)(row0 + r) * N + col] = v;
                }
            }
        }
    }
}

// ---------------- flash attention (no-max streaming softmax) ----------------
// ROUND-10 VERIFIED KERNEL, unchanged. 512 threads, 8 waves, QROWS=256;
// counted-vmcnt dbuf K/V staging; swapped QK^T with sigma-permuted K rows;
// in-register P->bf16; row sums via MFMA vs ones; setprio; XCD swizzle.
__global__ __launch_bounds__(512, 4) void attn(const unsigned short* __restrict__ Q,
                                               const unsigned short* __restrict__ Kp,
                                               const unsigned short* __restrict__ Vt,
                                               unsigned short* __restrict__ O) {
    __shared__ unsigned short KVs[2][2][64 * 64];   // [buf][K|V]  32 KB

    const int tid  = threadIdx.x;
    const int lane = tid & 63;
    const int wave = tid >> 6;          // 0..7
    const int l15  = lane & 15;
    const int quad = lane >> 4;

    // XCD swizzle: lin over (b,h,qt), 512 blocks, chunk = 64 per XCD
    const int lin = ((blockIdx.z * HEADS + blockIdx.y) << 3) | blockIdx.x;
    const int swz = ((lin & 7) << 6) | (lin >> 3);
    const int qt = swz & 7;
    const int h  = (swz >> 3) & 15;
    const int b  = swz >> 7;

    const size_t rowbase = (size_t)b * SEQ;
    const int colbase = h * HDIM;
    const size_t vtbase = (size_t)(b * HEADS + h) * HDIM;

    // prologue: stage K/V tile 0 into buffer 0 (K rows permuted by sigma);
    // 512 threads x 1 slot each per operand (64x64 bf16 = 512 x 16B slots)
    {
        int j = tid;
        int r = j >> 3;
        int sr = (r & 35) | ((r & 12) << 1) | ((r & 16) >> 2);
        int c8 = (j & 7) ^ (r & 7);
        __builtin_amdgcn_global_load_lds(GLB_U32(Kp + (rowbase + sr) * EMBED + colbase + c8 * 8),
                                         LDS_U32(KVs[0][0] + j * 8), 16, 0, 0);
        __builtin_amdgcn_global_load_lds(GLB_U32(Vt + (vtbase + r) * SEQ + c8 * 8),
                                         LDS_U32(KVs[0][1] + j * 8), 16, 0, 0);
    }

    // Q fragments straight from global (drained by the first vmcnt wait,
    // as they are older in the queue than tile 1's loads).
    bf16x8 aq[2][2];
#pragma unroll
    for (int mf = 0; mf < 2; ++mf) {
        const unsigned short* qp =
            Q + (rowbase + qt * QROWS + wave * 32 + mf * 16 + l15) * EMBED + colbase;
#pragma unroll
        for (int ks = 0; ks < 2; ++ks)
            aq[mf][ks] = *(const bf16x8*)(qp + ks * 32 + quad * 8);
    }

    // constants: zero C for first QK MFMA, ones B-fragment for row sums
    const f32x4 fz = {0.0f, 0.0f, 0.0f, 0.0f};
    bf16x8 vone;
#pragma unroll
    for (int i = 0; i < 8; ++i) vone[i] = (__bf16)1.0f;

    f32x4 oacc[2][4] = {};
    f32x4 sumacc[2] = {};

    for (int t = 0; t < 32; ++t) {
        const int cur = t & 1;
        if (t + 1 < 32) {
            int nb = cur ^ 1;
            int j = tid;
            int r = j >> 3;
            int sr = (r & 35) | ((r & 12) << 1) | ((r & 16) >> 2);
            int c8 = (j & 7) ^ (r & 7);
            __builtin_amdgcn_global_load_lds(GLB_U32(Kp + (rowbase + (t + 1) * 64 + sr) * EMBED + colbase + c8 * 8),
                                             LDS_U32(KVs[nb][0] + j * 8), 16, 0, 0);
            __builtin_amdgcn_global_load_lds(GLB_U32(Vt + (vtbase + r) * SEQ + (t + 1) * 64 + c8 * 8),
                                             LDS_U32(KVs[nb][1] + j * 8), 16, 0, 0);
            asm volatile("s_waitcnt vmcnt(2)" ::: "memory");  // tile t landed; t+1 in flight
        } else {
            asm volatile("s_waitcnt vmcnt(0)" ::: "memory");  // last tile: drain
        }
        __builtin_amdgcn_s_barrier();      // all waves see tile t in LDS

        const unsigned short* Ks = KVs[cur][0];
        const unsigned short* Vs = KVs[cur][1];

        // S'^T = K'.Q'^T ; ks=0 seeds from the hoisted zero (no per-iter init)
        f32x4 sacc[2][4];
        __builtin_amdgcn_s_setprio(1);
#pragma unroll
        for (int nf = 0; nf < 4; ++nf) {
            int krow = nf * 16 + l15;
            int ch = quad ^ (krow & 7);
            bf16x8 bk = *(const bf16x8*)(Ks + krow * 64 + ch * 8);
            sacc[0][nf] = __builtin_amdgcn_mfma_f32_16x16x32_bf16(bk, aq[0][0], fz, 0, 0, 0);
            sacc[1][nf] = __builtin_amdgcn_mfma_f32_16x16x32_bf16(bk, aq[1][0], fz, 0, 0, 0);
        }
#pragma unroll
        for (int nf = 0; nf < 4; ++nf) {
            int krow = nf * 16 + l15;
            int ch = (4 + quad) ^ (krow & 7);
            bf16x8 bk = *(const bf16x8*)(Ks + krow * 64 + ch * 8);
            sacc[0][nf] = __builtin_amdgcn_mfma_f32_16x16x32_bf16(bk, aq[0][1], sacc[0][nf], 0, 0, 0);
            sacc[1][nf] = __builtin_amdgcn_mfma_f32_16x16x32_bf16(bk, aq[1][1], sacc[1][nf], 0, 0, 0);
        }
        __builtin_amdgcn_s_setprio(0);

        // p = exp2(s'); RNE-convert to bf16 PV A-fragments fully in-register.
        // (nf, r) -> fragment [ks = nf>>1], element j = 4*(nf&1) + r.
        bf16x8 apv[2][2];
#pragma unroll
        for (int mf = 0; mf < 2; ++mf)
#pragma unroll
            for (int nf = 0; nf < 4; ++nf) {
                int ks2 = nf >> 1;
                int jb = (nf & 1) * 4;
                apv[mf][ks2][jb + 0] = (__bf16)__builtin_amdgcn_exp2f(sacc[mf][nf][0]);
                apv[mf][ks2][jb + 1] = (__bf16)__builtin_amdgcn_exp2f(sacc[mf][nf][1]);
                apv[mf][ks2][jb + 2] = (__bf16)__builtin_amdgcn_exp2f(sacc[mf][nf][2]);
                apv[mf][ks2][jb + 3] = (__bf16)__builtin_amdgcn_exp2f(sacc[mf][nf][3]);
            }

        // row sums via MFMA (B = ones): out[q][*] = sum_k p, row = quad*4+r
        // O += P.V
        __builtin_amdgcn_s_setprio(1);
#pragma unroll
        for (int ks = 0; ks < 2; ++ks) {
            sumacc[0] = __builtin_amdgcn_mfma_f32_16x16x32_bf16(apv[0][ks], vone, sumacc[0], 0, 0, 0);
            sumacc[1] = __builtin_amdgcn_mfma_f32_16x16x32_bf16(apv[1][ks], vone, sumacc[1], 0, 0, 0);
#pragma unroll
            for (int df = 0; df < 4; ++df) {
                int vrow = df * 16 + l15;
                int ch = (ks * 4 + quad) ^ (vrow & 7);
                bf16x8 bv = *(const bf16x8*)(Vs + vrow * 64 + ch * 8);
                oacc[0][df] = __builtin_amdgcn_mfma_f32_16x16x32_bf16(apv[0][ks], bv, oacc[0][df], 0, 0, 0);
                oacc[1][df] = __builtin_amdgcn_mfma_f32_16x16x32_bf16(apv[1][ks], bv, oacc[1][df], 0, 0, 0);
            }
        }
        __builtin_amdgcn_s_setprio(0);
        __builtin_amdgcn_s_barrier();      // all waves done reading buf[cur]
    }

    // epilogue: sumacc[mf][r] already holds the row sum for row quad*4+r
    // (same mapping as oacc) -> no cross-lane moves needed.
    float rinv[2][4];
#pragma unroll
    for (int mf = 0; mf < 2; ++mf)
#pragma unroll
        for (int r = 0; r < 4; ++r)
            rinv[mf][r] = 1.0f / sumacc[mf][r];

#pragma unroll
    for (int mf = 0; mf < 2; ++mf)
#pragma unroll
        for (int df = 0; df < 4; ++df) {
            int col = colbase + df * 16 + l15;
#pragma unroll
            for (int r = 0; r < 4; ++r) {
                int row = qt * QROWS + wave * 32 + mf * 16 + quad * 4 + r;
                O[(rowbase + row) * EMBED + col] = f2bf(oacc[mf][df][r] * rinv[mf][r]);
            }
        }
}

// ---------------- launch ----------------
extern "C" void kernel_launch(void* const* d_in, const int* in_sizes, int n_in,
                              void* d_out, int out_size, void* d_ws, size_t ws_size,
                              hipStream_t stream) {
    const float* q_in = (const float*)d_in[0];
    const float* k_in = (const float*)d_in[1];
    const float* v_in = (const float*)d_in[2];
    const float* Wq = (const float*)d_in[3];
    const float* bq = (const float*)d_in[4];
    const float* Wk = (const float*)d_in[5];
    const float* bk = (const float*)d_in[6];
    const float* Wv = (const float*)d_in[7];
    const float* bv = (const float*)d_in[8];
    const float* Wo = (const float*)d_in[9];
    const float* bo = (const float*)d_in[10];
    float* out = (float*)d_out;

    const size_t XE = (size_t)ROWS * EMBED;
    const size_t WE = (size_t)EMBED * EMBED;

    unsigned short* ws = (unsigned short*)d_ws;
    unsigned short* xq = ws;            // xq,xk,xv contiguous (fused QKV A-operand)
    unsigned short* wqkvo = xq + 3 * XE;  // 4 weight matrices contiguous
    unsigned short* wo = wqkvo + 3 * WE;
    unsigned short* Qp = wo + WE;       // Qp,Kp contiguous (fused QKV C, z=0/1)
    unsigned short* Kp = Qp + XE;
    unsigned short* vt = Kp + XE;       // V^T (written directly by the V projection)
    unsigned short* Ap = vt + XE;

    const float cexp = 0.045084436f;  // (1/32) * log2(e), folded into Q projection

    cvt_all<<<dim3(28672), 256, 0, stream>>>(q_in, k_in, v_in, Wq, Wk, Wv, Wo, xq, wqkvo);

    // fused Q/K/V projections (Q gets the softmax scale); V written transposed
    gemm_bt<true, true><<<dim3(EMBED / 128, ROWS / 128, 3), 512, 0, stream>>>(
        xq, wqkvo, bq, bk, bv, Qp, vt, cexp, ROWS, EMBED, EMBED);

    attn<<<dim3(SEQ / QROWS, HEADS, BATCH), 512, 0, stream>>>(Qp, Kp, vt, Ap);

    gemm_bt<false, false><<<dim3(EMBED / 128, ROWS / 128), 512, 0, stream>>>(
        Ap, wo, bo, nullptr, nullptr, out, nullptr, 1.0f, ROWS, EMBED, EMBED);
}